// Round 8
// baseline (17019.571 us; speedup 1.0000x reference)
//
#include <hip/hip_runtime.h>

// MI-LSTM, B=32, T=512, H=1024, L=2.  Persistent kernel, fence-free coherence:
//  - 256 blocks x 256 thr, 1 block/CU (149 KB LDS). Weights hi-bf16 in LDS (128 KB/CU).
//  - Weight lo-residual as INT8 with per-column scale (r8): lo = w - bf16(w),
//    q = round(lo/s), s = max_k|lo|/127 per (mat,col).  16 MB stream (vs 32 MB bf16)
//    -> 2 MB/XCD -> L2-RESIDENT (the bf16 stream was exactly at 4MB/XCD L2 capacity
//    and thrashed to MALL, latency-bound ~810 GB/s across r3-r6).  int8 -> bf16
//    expansion is EXACT (integers <=255 fit bf16's 8 sig bits): cvt_ubyte, -128,
//    truncate.  Separate MFMA accumulators for the q path; scale applied at the
//    epilogue (per-lane scalar hoisted out of the time loop).
//    Accuracy anchor: r7 (lo dropped entirely) -> absmax 0.34; int8-colscale error
//    is ~1/30-1/60 of full-lo -> predicted 0.006-0.013 vs threshold 0.0199.
//  - gates: cross-XCD via MALL-coherent accesses (sc0+sc1 bypass L1/L2).
//    Phase B reads them as WIDE dwordx4 sc0 sc1 loads; col ownership j = 4*tid + k.
//  - phase B (LN+pointwise) replicated per XCD (slot = HW_REG_XCC_ID, rank via census):
//    h hi/lo planes are per-XCD copies, same-L2 coherent, PLAIN stores/loads.
//    Parity double-buffer on gates and h planes; buffer_inv sc0 (L1-only) per barrier.
//  - Barriers: relaxed monotonic counters, per-slot tree -> root, epoch = tick+1.

#define TSTEPS 512
#define BATCH  32
#define HDIM   1024
#define GDIM   4096
#define NBLK   256
#define NTHR   256
#define CPB    16
#define KPAD   1032   // elements; row stride 2064 B (16B aligned)

typedef __attribute__((ext_vector_type(8))) short short8;
typedef __attribute__((ext_vector_type(4))) float f32x4;

// ---- ws layout (bytes) ----
#define WQ8_OFF   0u           // 16 MB: int8 lo-residual of W0,U0,W1,U1 [mat][col][k]
#define WSC_OFF   16777216u    // 64 KB: per-column scales [mat][col] f32
#define HPL_OFF   33554432u    // 4 MB: h planes [slot(8)][parity(2)][plane(4)] 64 KB each
#define G_OFF     37748736u    // 2 MB: gates [layer(2)][parity(2)] 512 KB each
#define SYNC_OFF  39845888u    // 4 KB sync words
#define SMEM_BYTES 152640

// sync word indices (4B units, 64B-spaced lines)
#define SW_CENSUS(s)  ((s) * 16)
#define SW_FCNT       128
#define SW_SCNT(s)    (144 + (s) * 16)
#define SW_ROOT       272
#define SW_LCNT(s)    (288 + (s) * 16)

#define AT_RLX __ATOMIC_RELAXED
#define SC_AGT __HIP_MEMORY_SCOPE_AGENT

__device__ __forceinline__ unsigned f2bf(float f) {
  unsigned u = __float_as_uint(f);
  return (u + 0x7FFFu + ((u >> 16) & 1u)) >> 16;   // RNE fp32 -> bf16 bits
}
__device__ __forceinline__ float sigm(float x) { return 1.f / (1.f + __expf(-x)); }
__device__ __forceinline__ float tanh_(float x) { return 1.f - 2.f / (__expf(2.f * x) + 1.f); }

__device__ __forceinline__ void split8(float4 a, float4 b, short8& hi, short8& lo) {
  float f[8] = {a.x, a.y, a.z, a.w, b.x, b.y, b.z, b.w};
  #pragma unroll
  for (int i = 0; i < 8; ++i) {
    unsigned h = f2bf(f[i]);
    hi[i] = (short)h;
    lo[i] = (short)f2bf(f[i] - __uint_as_float(h << 16));
  }
}

// 8 biased-u8 (q+128) -> bf16 of (q) EXACTLY (|q|<=127 fits bf16's 8 sig bits).
__device__ __forceinline__ short8 expand_q8(uint2 v) {
  short8 r;
  #pragma unroll
  for (int j = 0; j < 2; ++j) {
    unsigned u = j ? v.y : v.x;
    #pragma unroll
    for (int b = 0; b < 4; ++b) {
      float f = (float)((u >> (8 * b)) & 0xffu) - 128.f;   // v_cvt_f32_ubyteN + add
      r[j * 4 + b] = (short)(__float_as_uint(f) >> 16);    // exact truncation
    }
  }
  return r;
}

__device__ __forceinline__ int xcc_id() {
  // s_getreg(HW_REG_XCC_ID=20, offset 0, size 4)
  return (int)(__builtin_amdgcn_s_getreg(20 | (3 << 11)) & 7);
}

__device__ __forceinline__ unsigned short* hplane(unsigned char* hbase, int slot, int par, int pl) {
  return (unsigned short*)(hbase + ((unsigned)((slot * 8 + par * 4 + pl)) << 16));
}
__device__ __forceinline__ float* gbase(unsigned char* gb, int l, int par) {
  return (float*)(gb + ((unsigned)(l * 2 + par) << 19));
}

// global barrier #ep (ep = 1,2,...): per-slot monotonic counter -> root.
__device__ __forceinline__ void gbar(unsigned* sync, int slot, int n, int nslots, unsigned ep) {
  __syncthreads();                       // compiler emits vmcnt(0) drain before s_barrier
  if (threadIdx.x == 0) {
    unsigned a = __hip_atomic_fetch_add(sync + SW_SCNT(slot), 1u, AT_RLX, SC_AGT);
    if (a == (unsigned)n * ep - 1u)      // last arriver of this slot for barrier #ep
      __hip_atomic_fetch_add(sync + SW_ROOT, 1u, AT_RLX, SC_AGT);
    while (__hip_atomic_load(sync + SW_ROOT, AT_RLX, SC_AGT) < (unsigned)nslots * ep)
      __builtin_amdgcn_s_sleep(4);
  }
  __syncthreads();
  asm volatile("buffer_inv sc0" ::: "memory");           // L1-only invalidate
}

// XCD-local barrier: monotonic per-slot counter, target = n * (tick+1)
__device__ __forceinline__ void lbar(unsigned* sync, int slot, unsigned target) {
  __syncthreads();
  if (threadIdx.x == 0) {
    __hip_atomic_fetch_add(sync + SW_LCNT(slot), 1u, AT_RLX, SC_AGT);
    while (__hip_atomic_load(sync + SW_LCNT(slot), AT_RLX, SC_AGT) < target)
      __builtin_amdgcn_s_sleep(2);
  }
  __syncthreads();
  asm volatile("buffer_inv sc0" ::: "memory");           // L1-only invalidate
}

__device__ __forceinline__ void bred(float& s, float& q, volatile float* red, int tid) {
  #pragma unroll
  for (int o = 32; o > 0; o >>= 1) {
    s += __shfl_xor(s, o, 64);
    q += __shfl_xor(q, o, 64);
  }
  __syncthreads();
  if ((tid & 63) == 0) { int w = tid >> 6; red[w] = s; red[w + 4] = q; }
  __syncthreads();
  s = red[0] + red[1] + red[2] + red[3];
  q = red[4] + red[5] + red[6] + red[7];
  __syncthreads();
}

// Register-resident pointwise, VECTORIZED: thread t owns columns {4t..4t+3} of each
// gate (i = cols 0..1023, f 1024.., g 2048.., o 3072..).  Gate loads are 4x dwordx4
// with sc0+sc1 (bypass L1/L2 -> MALL-fresh), all other accesses 16B/8B vectors.
__device__ __forceinline__ void pointwise2(
    int l, int r, int t, const float* __restrict__ gbuf,
    const float* __restrict__ lngw, const float* __restrict__ lngb,
    const float* __restrict__ lncw, const float* __restrict__ lncb,
    unsigned short* __restrict__ hhi, unsigned short* __restrict__ hlo,
    float* __restrict__ y, float* cst, volatile float* red, int tid)
{
  const float* grow = gbuf + (size_t)r * GDIM;
  const int j0 = tid * 4;                       // 4 contiguous cols per gate
  const float* p0 = grow + j0;                  // i gate
  const float* p1 = grow + 1024 + j0;           // f gate
  const float* p2 = grow + 2048 + j0;           // g gate
  const float* p3 = grow + 3072 + j0;           // o gate
  f32x4 v0, v1, v2, v3;
  asm volatile(
    "global_load_dwordx4 %0, %4, off sc0 sc1\n\t"
    "global_load_dwordx4 %1, %5, off sc0 sc1\n\t"
    "global_load_dwordx4 %2, %6, off sc0 sc1\n\t"
    "global_load_dwordx4 %3, %7, off sc0 sc1\n\t"
    "s_waitcnt vmcnt(0)"
    : "=&v"(v0), "=&v"(v1), "=&v"(v2), "=&v"(v3)
    : "v"(p0), "v"(p1), "v"(p2), "v"(p3)
    : "memory");

  float vals[16];
  #pragma unroll
  for (int k = 0; k < 4; ++k) {
    vals[k]      = v0[k];
    vals[4 + k]  = v1[k];
    vals[8 + k]  = v2[k];
    vals[12 + k] = v3[k];
  }
  float s = 0.f, qq = 0.f;
  #pragma unroll
  for (int i = 0; i < 16; ++i) { s += vals[i]; qq += vals[i] * vals[i]; }
  bred(s, qq, red, tid);
  float m1  = s * (1.f / (float)GDIM);
  float var = qq * (1.f / (float)GDIM) - m1 * m1;
  float inv = rsqrtf(var + 1e-5f);

  float ln[16];
  #pragma unroll
  for (int g = 0; g < 4; ++g) {
    f32x4 gw = *(const f32x4*)(lngw + (size_t)l * GDIM + g * 1024 + j0);
    f32x4 gbv = *(const f32x4*)(lngb + (size_t)l * GDIM + g * 1024 + j0);
    #pragma unroll
    for (int k = 0; k < 4; ++k)
      ln[g * 4 + k] = (vals[g * 4 + k] - m1) * inv * gw[k] + gbv[k];
  }

  f32x4 cold = *(const f32x4*)(cst + j0);
  float cv[4];
  float s2 = 0.f, q2 = 0.f;
  #pragma unroll
  for (int k = 0; k < 4; ++k) {
    float gi = sigm(ln[k]);          // i gate
    float gf = sigm(ln[4 + k]);      // f gate
    float gg = tanh_(ln[8 + k]);     // g gate
    float c  = gf * cold[k] + gi * gg;
    cv[k] = c; s2 += c; q2 += c * c;
  }
  bred(s2, q2, red, tid);
  float m2   = s2 * (1.f / (float)HDIM);
  float vv2  = q2 * (1.f / (float)HDIM) - m2 * m2;
  float inv2 = rsqrtf(vv2 + 1e-5f);

  f32x4 cw = *(const f32x4*)(lncw + (size_t)l * HDIM + j0);
  f32x4 cb = *(const f32x4*)(lncb + (size_t)l * HDIM + j0);
  f32x4 cnew, hv;
  unsigned hhp[4], hlp[4];
  #pragma unroll
  for (int k = 0; k < 4; ++k) {
    float cn = (cv[k] - m2) * inv2 * cw[k] + cb[k];
    cnew[k] = cn;
    float h = sigm(ln[12 + k]) * tanh_(cn);      // o gate
    hv[k] = h;
    unsigned hh = f2bf(h);
    hhp[k] = hh;
    hlp[k] = f2bf(h - __uint_as_float(hh << 16));
  }
  *(f32x4*)(cst + j0) = cnew;                    // carried state (post-LN, as in ref)
  uint2 uh, ul;
  uh.x = hhp[0] | (hhp[1] << 16);  uh.y = hhp[2] | (hhp[3] << 16);
  ul.x = hlp[0] | (hlp[1] << 16);  ul.y = hlp[2] | (hlp[3] << 16);
  // PLAIN stores: same-XCD consumers read through the shared L2 (coherent);
  // consumer L1 staleness handled by buffer_inv sc0 at the barrier.
  *(uint2*)(hhi + (size_t)r * HDIM + j0) = uh;
  *(uint2*)(hlo + (size_t)r * HDIM + j0) = ul;
  if (y) *(f32x4*)(y + ((size_t)r * TSTEPS + t) * HDIM + j0) = hv;
}

extern "C" __global__ void __launch_bounds__(NTHR, 1)
milstm_main(const float* __restrict__ x,
            const float* __restrict__ Wm, const float* __restrict__ bv,
            const float* __restrict__ Um,
            const float* __restrict__ lngw, const float* __restrict__ lngb,
            const float* __restrict__ lncw, const float* __restrict__ lncb,
            unsigned char* __restrict__ ws, float* __restrict__ y)
{
  extern __shared__ unsigned char smem[];
  unsigned short* wlds = (unsigned short*)smem;            // 132096 B
  float* clds = (float*)(smem + 132096);                   // 5 * 4096 B c-state slots
  volatile float* red = (volatile float*)(smem + 152576);  // 64 B

  const unsigned char* wq8 = (const unsigned char*)(ws + WQ8_OFF);
  const float* wsc = (const float*)(ws + WSC_OFF);
  unsigned char* hbase = ws + HPL_OFF;
  unsigned char* gb    = ws + G_OFF;
  unsigned* sync       = (unsigned*)(ws + SYNC_OFF);

  const int tid = threadIdx.x;
  const int bk  = blockIdx.x;
  const int c0  = bk * CPB;

  // ---- preload hi-part weight slices into LDS (mat: 0=W0 1=U0 2=W1 3=U1) ----
  #pragma unroll 4
  for (int it = 0; it < 64; ++it) {
    int idx = it * NTHR + tid;
    int mat = idx >> 12;
    int rem = idx & 4095;
    int row = rem >> 8;
    int k4  = rem & 255;
    int l   = mat >> 1;
    const float* src = ((mat & 1) ? Um : Wm) + (size_t)(l * GDIM + c0 + row) * HDIM + k4 * 4;
    float4 f = *(const float4*)src;
    uint2 u;
    u.x = f2bf(f.x) | (f2bf(f.y) << 16);
    u.y = f2bf(f.z) | (f2bf(f.w) << 16);
    *(uint2*)(wlds + (size_t)(mat * CPB + row) * KPAD + k4 * 4) = u;
  }
  for (int i = tid; i < 5 * HDIM; i += NTHR) clds[i] = 0.f;   // c-state = 0

  // ---- census: slot (XCD) + rank within slot ----
  __shared__ int sh_slot, sh_rank, sh_n, sh_nslots;
  __syncthreads();
  if (tid == 0) {
    int s = xcc_id();
    sh_slot = s;
    sh_rank = (int)__hip_atomic_fetch_add(sync + SW_CENSUS(s), 1u, AT_RLX, SC_AGT);
    __hip_atomic_fetch_add(sync + SW_FCNT, 1u, AT_RLX, SC_AGT);
    while (__hip_atomic_load(sync + SW_FCNT, AT_RLX, SC_AGT) < (unsigned)NBLK)
      __builtin_amdgcn_s_sleep(4);
    asm volatile("" ::: "memory");
    int ns = 0, nn = 0;
    for (int i = 0; i < 8; ++i) {
      int c = (int)__hip_atomic_load(sync + SW_CENSUS(i), AT_RLX, SC_AGT);
      if (c > 0) ns++;
      if (i == s) nn = c;
    }
    sh_n = nn; sh_nslots = ns;
  }
  __syncthreads();
  const int slot = sh_slot, rank = sh_rank, n = sh_n, nslots = sh_nslots;

  const int lane = tid & 63;
  const int wv   = tid >> 6;
  const int Lw   = wv >> 1;       // layer for this wave in phase A
  const int mt   = wv & 1;        // M-tile (batch rows 0..15 / 16..31)
  const int q    = lane >> 4;
  const int r16  = lane & 15;
  const int arow = mt * 16 + r16;

  const unsigned short* bxh = wlds + (size_t)((Lw * 2 + 0) * CPB + r16) * KPAD + q * 8;
  const unsigned short* buh = wlds + (size_t)((Lw * 2 + 1) * CPB + r16) * KPAD + q * 8;
  const unsigned char* bxq = wq8 + ((size_t)((Lw * 2 + 0) * GDIM) + c0 + r16) * HDIM + q * 8;
  const unsigned char* buq = wq8 + ((size_t)((Lw * 2 + 1) * GDIM) + c0 + r16) * HDIM + q * 8;
  const float sw = wsc[(Lw * 2 + 0) * GDIM + c0 + r16];   // per-column scales (hoisted)
  const float su = wsc[(Lw * 2 + 1) * GDIM + c0 + r16];
  const float bias_v = bv[Lw * GDIM + c0 + r16];

  for (int tk = 0; tk <= TSTEPS; ++tk) {
    // -------- phase A: split-bf16 + int8-lo gates GEMMs (layer0@tk, layer1@tk-1) ----
    const bool act = (Lw == 0) ? (tk < TSTEPS) : (tk >= 1);
    if (act) {
      // h input parities: h0@tk-1 -> (tk+1)&1 ; h1@tk-2 -> tk&1
      const unsigned short* p0hi = hplane(hbase, slot, (tk + 1) & 1, 0);
      const unsigned short* p0lo = hplane(hbase, slot, (tk + 1) & 1, 1);
      f32x4 accx  = {0.f, 0.f, 0.f, 0.f};
      f32x4 acch  = {0.f, 0.f, 0.f, 0.f};
      f32x4 accqx = {0.f, 0.f, 0.f, 0.f};
      f32x4 accqh = {0.f, 0.f, 0.f, 0.f};
      if (Lw == 0) {
        const float* xp = x + ((size_t)arow * TSTEPS + tk) * HDIM + q * 8;
        const unsigned short* hh = p0hi + arow * HDIM + q * 8;
        const unsigned short* hl = p0lo + arow * HDIM + q * 8;
        // rotating register prefetch: h/x (L2-hot) and int8 lo (L2-resident)
        short8 hhb[4], hlb[4];
        float4 fab[4], fbb[4];
        uint2 wqb[4], uqb[4];
        #pragma unroll
        for (int i = 0; i < 4; ++i) {
          hhb[i] = *(const short8*)(hh + i * 32);
          hlb[i] = *(const short8*)(hl + i * 32);
          fab[i] = *(const float4*)(xp + i * 32);
          fbb[i] = *(const float4*)(xp + i * 32 + 4);
          wqb[i] = *(const uint2*)(bxq + i * 32);
          uqb[i] = *(const uint2*)(buq + i * 32);
        }
        #pragma unroll 4
        for (int ch = 0; ch < 32; ++ch) {
          float4 fa = fab[ch & 3], fb = fbb[ch & 3];
          short8 ahh = hhb[ch & 3], ahl = hlb[ch & 3];
          uint2 wq = wqb[ch & 3], uq = uqb[ch & 3];
          if (ch + 4 < 32) {
            hhb[ch & 3] = *(const short8*)(hh + (ch + 4) * 32);
            hlb[ch & 3] = *(const short8*)(hl + (ch + 4) * 32);
            fab[ch & 3] = *(const float4*)(xp + (ch + 4) * 32);
            fbb[ch & 3] = *(const float4*)(xp + (ch + 4) * 32 + 4);
            wqb[ch & 3] = *(const uint2*)(bxq + (ch + 4) * 32);
            uqb[ch & 3] = *(const uint2*)(buq + (ch + 4) * 32);
          }
          short8 axh, axl; split8(fa, fb, axh, axl);
          short8 wl = expand_q8(wq);
          short8 ul = expand_q8(uq);
          short8 wh = *(const short8*)(bxh + ch * 32);
          short8 uh = *(const short8*)(buh + ch * 32);
          accx  = __builtin_amdgcn_mfma_f32_16x16x32_bf16(axh, wh, accx, 0, 0, 0);
          accx  = __builtin_amdgcn_mfma_f32_16x16x32_bf16(axl, wh, accx, 0, 0, 0);
          accqx = __builtin_amdgcn_mfma_f32_16x16x32_bf16(axh, wl, accqx, 0, 0, 0);
          acch  = __builtin_amdgcn_mfma_f32_16x16x32_bf16(ahh, uh, acch, 0, 0, 0);
          acch  = __builtin_amdgcn_mfma_f32_16x16x32_bf16(ahl, uh, acch, 0, 0, 0);
          accqh = __builtin_amdgcn_mfma_f32_16x16x32_bf16(ahh, ul, accqh, 0, 0, 0);
        }
      } else {
        const unsigned short* p1hi = hplane(hbase, slot, tk & 1, 2);
        const unsigned short* p1lo = hplane(hbase, slot, tk & 1, 3);
        const unsigned short* gh_ = p0hi + arow * HDIM + q * 8;
        const unsigned short* gl_ = p0lo + arow * HDIM + q * 8;
        const unsigned short* hh  = p1hi + arow * HDIM + q * 8;
        const unsigned short* hl  = p1lo + arow * HDIM + q * 8;
        short8 axhb[4], axlb[4], ahhb[4], ahlb[4];
        uint2 wqb[4], uqb[4];
        #pragma unroll
        for (int i = 0; i < 4; ++i) {
          axhb[i] = *(const short8*)(gh_ + i * 32);
          axlb[i] = *(const short8*)(gl_ + i * 32);
          ahhb[i] = *(const short8*)(hh + i * 32);
          ahlb[i] = *(const short8*)(hl + i * 32);
          wqb[i] = *(const uint2*)(bxq + i * 32);
          uqb[i] = *(const uint2*)(buq + i * 32);
        }
        #pragma unroll 4
        for (int ch = 0; ch < 32; ++ch) {
          short8 axh = axhb[ch & 3], axl = axlb[ch & 3];
          short8 ahh = ahhb[ch & 3], ahl = ahlb[ch & 3];
          uint2 wq = wqb[ch & 3], uq = uqb[ch & 3];
          if (ch + 4 < 32) {
            axhb[ch & 3] = *(const short8*)(gh_ + (ch + 4) * 32);
            axlb[ch & 3] = *(const short8*)(gl_ + (ch + 4) * 32);
            ahhb[ch & 3] = *(const short8*)(hh + (ch + 4) * 32);
            ahlb[ch & 3] = *(const short8*)(hl + (ch + 4) * 32);
            wqb[ch & 3] = *(const uint2*)(bxq + (ch + 4) * 32);
            uqb[ch & 3] = *(const uint2*)(buq + (ch + 4) * 32);
          }
          short8 wl = expand_q8(wq);
          short8 ul = expand_q8(uq);
          short8 wh = *(const short8*)(bxh + ch * 32);
          short8 uh = *(const short8*)(buh + ch * 32);
          accx  = __builtin_amdgcn_mfma_f32_16x16x32_bf16(axh, wh, accx, 0, 0, 0);
          accx  = __builtin_amdgcn_mfma_f32_16x16x32_bf16(axl, wh, accx, 0, 0, 0);
          accqx = __builtin_amdgcn_mfma_f32_16x16x32_bf16(axh, wl, accqx, 0, 0, 0);
          acch  = __builtin_amdgcn_mfma_f32_16x16x32_bf16(ahh, uh, acch, 0, 0, 0);
          acch  = __builtin_amdgcn_mfma_f32_16x16x32_bf16(ahl, uh, acch, 0, 0, 0);
          accqh = __builtin_amdgcn_mfma_f32_16x16x32_bf16(ahh, ul, accqh, 0, 0, 0);
        }
      }
      float* gbuf = (Lw == 0) ? gbase(gb, 0, tk & 1) : gbase(gb, 1, (tk - 1) & 1);
      #pragma unroll
      for (int rg = 0; rg < 4; ++rg) {
        float gx = accx[rg] + sw * accqx[rg] + bias_v;   // gx = x@W.T + b (hi + s*q)
        float gh = acch[rg] + su * accqh[rg];
        int row = mt * 16 + q * 4 + rg;   // C/D: col=lane&15, row=quad*4+reg
        __hip_atomic_store(&gbuf[row * GDIM + c0 + r16], gx + gh + gx * gh, AT_RLX, SC_AGT);
      }
    }
    gbar(sync, slot, n, nslots, (unsigned)(tk + 1));

    // -------- phase B: replicated per XCD; rank r takes tasks r, r+n, ... of 64 --------
    for (int task = rank; task < 64; task += n) {
      int o = (task - rank) / n;
      if (o >= 5) break;                  // c-state LDS capacity guard
      int l = task >> 5, r = task & 31;
      float* cst = clds + o * HDIM;
      if (l == 0) {
        if (tk < TSTEPS)
          pointwise2(0, r, tk, gbase(gb, 0, tk & 1), lngw, lngb, lncw, lncb,
                     hplane(hbase, slot, tk & 1, 0), hplane(hbase, slot, tk & 1, 1),
                     (float*)0, cst, red, tid);
      } else {
        if (tk >= 1)
          pointwise2(1, r, tk - 1, gbase(gb, 1, (tk - 1) & 1), lngw, lngb, lncw, lncb,
                     hplane(hbase, slot, (tk - 1) & 1, 2), hplane(hbase, slot, (tk - 1) & 1, 3),
                     y, cst, red, tid);
      }
    }
    lbar(sync, slot, (unsigned)n * (unsigned)(tk + 1));
  }
}

// int8 per-column-scale lo-residual: one wave per (mat,col); lane owns 16 k-elems.
extern "C" __global__ void __launch_bounds__(64)
milstm_prep_wq8(const float* __restrict__ Wm, const float* __restrict__ Um,
                unsigned char* __restrict__ wq8, float* __restrict__ wsc)
{
  int b = blockIdx.x;          // 16384 = 4 mats * 4096 cols
  int mat = b >> 12;
  int col = b & 4095;
  int lane = threadIdx.x;      // 64
  const float* src = ((mat & 1) ? Um : Wm)
                   + ((size_t)((mat >> 1) * GDIM + col)) * HDIM + lane * 16;
  float lo[16];
  float m = 0.f;
  #pragma unroll
  for (int i = 0; i < 4; ++i) {
    float4 f = *(const float4*)(src + i * 4);
    float w4[4] = {f.x, f.y, f.z, f.w};
    #pragma unroll
    for (int j = 0; j < 4; ++j) {
      unsigned hb = f2bf(w4[j]);
      float l_ = w4[j] - __uint_as_float(hb << 16);
      lo[i * 4 + j] = l_;
      m = fmaxf(m, fabsf(l_));
    }
  }
  #pragma unroll
  for (int o = 32; o > 0; o >>= 1) m = fmaxf(m, __shfl_xor(m, o, 64));
  float s = (m > 0.f) ? (m * (1.f / 127.f)) : 1.f;
  float rs = 1.f / s;
  unsigned bytes[16];
  #pragma unroll
  for (int i = 0; i < 16; ++i) {
    float qf = rintf(lo[i] * rs);
    qf = fminf(fmaxf(qf, -127.f), 127.f);
    bytes[i] = (unsigned)(int)(qf + 128.f);
  }
  uint4 u;
  u.x = bytes[0]  | (bytes[1]  << 8) | (bytes[2]  << 16) | (bytes[3]  << 24);
  u.y = bytes[4]  | (bytes[5]  << 8) | (bytes[6]  << 16) | (bytes[7]  << 24);
  u.z = bytes[8]  | (bytes[9]  << 8) | (bytes[10] << 16) | (bytes[11] << 24);
  u.w = bytes[12] | (bytes[13] << 8) | (bytes[14] << 16) | (bytes[15] << 24);
  *(uint4*)(wq8 + ((size_t)mat * GDIM + col) * HDIM + lane * 16) = u;
  if (lane == 0) wsc[mat * GDIM + col] = s;
}

extern "C" __global__ void __launch_bounds__(256)
milstm_prep_init(unsigned* __restrict__ hz, unsigned* __restrict__ sync)
{
  int v = blockIdx.x * 256 + threadIdx.x;
  if (v < 1048576) hz[v] = 0u;                    // h planes region (4 MB)
  else if (v < 1048576 + 1024) sync[v - 1048576] = 0u;   // sync words (4 KB)
}

extern "C" void kernel_launch(void* const* d_in, const int* in_sizes, int n_in,
                              void* d_out, int out_size, void* d_ws, size_t ws_size,
                              hipStream_t stream)
{
  const float* x    = (const float*)d_in[0];
  const float* Wm   = (const float*)d_in[1];
  const float* bv   = (const float*)d_in[2];
  const float* Um   = (const float*)d_in[3];
  const float* lngw = (const float*)d_in[4];
  const float* lngb = (const float*)d_in[5];
  const float* lncw = (const float*)d_in[6];
  const float* lncb = (const float*)d_in[7];
  float* y = (float*)d_out;

  unsigned char* ws = (unsigned char*)d_ws;
  unsigned char* wq8 = ws + WQ8_OFF;
  float* wsc = (float*)(ws + WSC_OFF);
  unsigned* hz   = (unsigned*)(ws + HPL_OFF);
  unsigned* sync = (unsigned*)(ws + SYNC_OFF);

  hipLaunchKernelGGL(milstm_prep_wq8, dim3(16384), dim3(64), 0, stream, Wm, Um, wq8, wsc);
  hipLaunchKernelGGL(milstm_prep_init, dim3(4101), dim3(256), 0, stream, hz, sync);
  (void)hipFuncSetAttribute((const void*)milstm_main,
                            hipFuncAttributeMaxDynamicSharedMemorySize, SMEM_BYTES);
  hipLaunchKernelGGL(milstm_main, dim3(NBLK), dim3(NTHR), SMEM_BYTES, stream,
                     x, Wm, bv, Um, lngw, lngb, lncw, lncb, ws, y);
}